// Round 1
// baseline (43.868 us; speedup 1.0000x reference)
//
#include <hip/hip_runtime.h>

// Problem constants (from reference):
//   B = 4096 rows, n = 2048, D = 2n = 4096 floats per row
//   sigma_var = 0.02, c = sqrt(0.98), s = sqrt(0.02)
//   xp   = c*x + s*w                       (elementwise)
//   logp = -25 * sum_row((c*x)^2) + const  (const = -0.5*D*log(2*pi*0.02))
// Output layout: [ xp (B*D floats) | logp broadcast (B*D floats) ]

constexpr int   ROWS   = 4096;
constexpr int   DIM    = 4096;                     // floats per row
constexpr int   DIM4   = DIM / 4;                  // float4 per row = 1024
constexpr float C_     = 0.98994949366116653f;     // sqrt(0.98)
constexpr float S_     = 0.14142135623730951f;     // sqrt(0.02)
constexpr float NEGHALF_OVER_VAR = -25.0f;         // -0.5 / 0.02
constexpr float LOGCONST = 4247.8508831105104f;    // -0.5*4096*log(2*pi*0.02)

__global__ __launch_bounds__(256)
void policy_kernel(const float4* __restrict__ x,
                   const float4* __restrict__ w,
                   float4* __restrict__ out_xp,
                   float4* __restrict__ out_lp) {
    const int row  = blockIdx.x;
    const int tid  = threadIdx.x;
    const int base = row * DIM4;                   // float4 index of row start

    float acc = 0.0f;

    #pragma unroll
    for (int i = 0; i < 4; ++i) {                  // 4 float4 per thread -> 1024/row
        const int idx = base + tid + i * 256;
        const float4 xv = x[idx];
        const float4 wv = w[idx];
        float4 o;
        const float d0 = C_ * xv.x;
        const float d1 = C_ * xv.y;
        const float d2 = C_ * xv.z;
        const float d3 = C_ * xv.w;
        o.x = fmaf(S_, wv.x, d0);
        o.y = fmaf(S_, wv.y, d1);
        o.z = fmaf(S_, wv.z, d2);
        o.w = fmaf(S_, wv.w, d3);
        out_xp[idx] = o;
        acc = fmaf(d0, d0, acc);
        acc = fmaf(d1, d1, acc);
        acc = fmaf(d2, d2, acc);
        acc = fmaf(d3, d3, acc);
    }

    // Wave-64 butterfly reduce, then cross-wave via LDS (4 waves/block).
    #pragma unroll
    for (int off = 32; off > 0; off >>= 1)
        acc += __shfl_down(acc, off, 64);

    __shared__ float wsum[4];
    if ((tid & 63) == 0) wsum[tid >> 6] = acc;
    __syncthreads();

    const float total = wsum[0] + wsum[1] + wsum[2] + wsum[3];
    const float logp  = fmaf(NEGHALF_OVER_VAR, total, LOGCONST);

    const float4 lp4 = make_float4(logp, logp, logp, logp);
    #pragma unroll
    for (int i = 0; i < 4; ++i) {
        out_lp[base + tid + i * 256] = lp4;
    }
}

extern "C" void kernel_launch(void* const* d_in, const int* in_sizes, int n_in,
                              void* d_out, int out_size, void* d_ws, size_t ws_size,
                              hipStream_t stream) {
    const float4* x = (const float4*)d_in[0];
    const float4* w = (const float4*)d_in[1];
    float* out = (float*)d_out;
    float4* out_xp = (float4*)out;                         // first 16,777,216 floats
    float4* out_lp = (float4*)(out + ROWS * DIM);          // next  16,777,216 floats

    policy_kernel<<<ROWS, 256, 0, stream>>>(x, w, out_xp, out_lp);
}